// Round 8
// baseline (53.172 us; speedup 1.0000x reference)
//
#include <hip/hip_runtime.h>

// pred: [T=2048, B=64, C=512] f32, mask: [T*B, 1] f32.
// loss = -sum_{p>0.9} p / max(cnt,1), 0 if cnt==0.
// Only the per-row argmax can exceed 0.9 (softmax sums to 1), so per row:
//   m = max(x), s = sum exp(x-m), pmax = 1/s; selected iff pmax > 0.9.
//
// Fused single kernel, cheap epilogue (R6 lesson: epilogue cost scales with
// block count — 2048 tickets + 4096 uncached loads was +5us; here 512 blocks
// x 1024 threads -> 512 tickets, 512 packed u64 partial loads ~ 1.5us).
// All cross-block traffic relaxed at the coherence point (R5 lesson: acq_rel/
// threadfence per block = serialized L2 flush, +125us). Plain cached loads
// (R4 lesson: nontemporal loads collapse streaming BW on gfx950).

#define NCLS 512
#define THRESH 0.9f
#define NBLOCKS 512
#define NTHREADS 1024
#define WAVES_PER_BLOCK 16

typedef float f32x4 __attribute__((ext_vector_type(4)));

__device__ __forceinline__ void row_reduce(f32x4 a, f32x4 b, float mval,
                                           float& wTotal, float& wCnt) {
    float x0 = a.x * mval, x1 = a.y * mval, x2 = a.z * mval, x3 = a.w * mval;
    float x4 = b.x * mval, x5 = b.y * mval, x6 = b.z * mval, x7 = b.w * mval;

    float mx = fmaxf(fmaxf(fmaxf(x0, x1), fmaxf(x2, x3)),
                     fmaxf(fmaxf(x4, x5), fmaxf(x6, x7)));
    #pragma unroll
    for (int off = 1; off < 64; off <<= 1)
        mx = fmaxf(mx, __shfl_xor(mx, off));

    float s = __expf(x0 - mx) + __expf(x1 - mx) + __expf(x2 - mx) + __expf(x3 - mx)
            + __expf(x4 - mx) + __expf(x5 - mx) + __expf(x6 - mx) + __expf(x7 - mx);
    #pragma unroll
    for (int off = 1; off < 64; off <<= 1)
        s += __shfl_xor(s, off);

    float pmax = 1.0f / s;          // prob of the argmax element
    if (pmax > THRESH) { wTotal += pmax; wCnt += 1.0f; }
}

__global__ __launch_bounds__(NTHREADS) void pl_fused(
        const float* __restrict__ pred,
        const float* __restrict__ mask,
        unsigned long long* __restrict__ partial,   // packed float2
        unsigned int* __restrict__ ticket,
        float* __restrict__ out,
        int N) {
    const int lane = threadIdx.x & 63;
    const int wid  = threadIdx.x >> 6;   // 16 waves per block

    const long long nwaves = (long long)gridDim.x * WAVES_PER_BLOCK;
    const long long wave   = (long long)blockIdx.x * WAVES_PER_BLOCK + wid;
    const long long rpw    = N / nwaves;          // 16 rows per wave here
    const long long base   = wave * rpw;
    const long long end    = base + rpw;

    float wTotal = 0.0f;
    float wCnt   = 0.0f;

    // contiguous stream per wave; unroll x4 keeps 8 loads (8KB/wave) in flight
    long long row = base;
    for (; row + 3 < end; row += 4) {
        const f32x4* rp0 = (const f32x4*)(pred + (row    ) * NCLS);
        const f32x4* rp1 = (const f32x4*)(pred + (row + 1) * NCLS);
        const f32x4* rp2 = (const f32x4*)(pred + (row + 2) * NCLS);
        const f32x4* rp3 = (const f32x4*)(pred + (row + 3) * NCLS);
        const float m0 = mask[row];
        const float m1 = mask[row + 1];
        const float m2 = mask[row + 2];
        const float m3 = mask[row + 3];
        f32x4 a0 = rp0[lane], b0 = rp0[lane + 64];
        f32x4 a1 = rp1[lane], b1 = rp1[lane + 64];
        f32x4 a2 = rp2[lane], b2 = rp2[lane + 64];
        f32x4 a3 = rp3[lane], b3 = rp3[lane + 64];
        row_reduce(a0, b0, m0, wTotal, wCnt);
        row_reduce(a1, b1, m1, wTotal, wCnt);
        row_reduce(a2, b2, m2, wTotal, wCnt);
        row_reduce(a3, b3, m3, wTotal, wCnt);
    }
    for (; row < end; ++row) {
        const float m1 = mask[row];
        const f32x4* rp1 = (const f32x4*)(pred + row * NCLS);
        f32x4 a1 = rp1[lane];
        f32x4 b1 = rp1[lane + 64];
        row_reduce(a1, b1, m1, wTotal, wCnt);
    }
    // tail rows if N % nwaves != 0 (not hit for 131072/8192)
    {
        long long tail = nwaves * rpw + wave;
        if (tail < (long long)N) {
            const float m1 = mask[tail];
            const f32x4* rp1 = (const f32x4*)(pred + tail * NCLS);
            f32x4 a1 = rp1[lane];
            f32x4 b1 = rp1[lane + 64];
            row_reduce(a1, b1, m1, wTotal, wCnt);
        }
    }

    __shared__ float sT[WAVES_PER_BLOCK];
    __shared__ float sC[WAVES_PER_BLOCK];
    __shared__ int sLast;
    if (lane == 0) { sT[wid] = wTotal; sC[wid] = wCnt; }
    __syncthreads();
    if (threadIdx.x == 0) {
        float t = 0.0f, c = 0.0f;
        #pragma unroll
        for (int i = 0; i < WAVES_PER_BLOCK; ++i) { t += sT[i]; c += sC[i]; }
        union { float2 f; unsigned long long u; } pub;
        pub.f = make_float2(t, c);
        // publish at the coherence point, relaxed (no L2 flush)
        __hip_atomic_store(&partial[blockIdx.x], pub.u, __ATOMIC_RELAXED,
                           __HIP_MEMORY_SCOPE_AGENT);
        // store ack -> globally visible
        asm volatile("s_waitcnt vmcnt(0)" ::: "memory");
        // relaxed ticket; 512 consecutive increments cover all residues
        // mod 512 -> exactly one block sees 511, for ANY start value
        unsigned int old = __hip_atomic_fetch_add(ticket, 1u, __ATOMIC_RELAXED,
                                                  __HIP_MEMORY_SCOPE_AGENT);
        sLast = ((old & (NBLOCKS - 1)) == (NBLOCKS - 1)) ? 1 : 0;
    }
    __syncthreads();

    if (sLast) {
        // unique last block: every other block's partial reached the
        // coherence point (vmcnt(0)) before its ticket RMW.
        float t = 0.0f, c = 0.0f;
        if (threadIdx.x < NBLOCKS) {
            union { float2 f; unsigned long long u; } got;
            got.u = __hip_atomic_load(&partial[threadIdx.x], __ATOMIC_RELAXED,
                                      __HIP_MEMORY_SCOPE_AGENT);
            t = got.f.x;
            c = got.f.y;
        }
        #pragma unroll
        for (int off = 1; off < 64; off <<= 1) {
            t += __shfl_xor(t, off);
            c += __shfl_xor(c, off);
        }
        __shared__ float fT[WAVES_PER_BLOCK];
        __shared__ float fC[WAVES_PER_BLOCK];
        if (lane == 0) { fT[wid] = t; fC[wid] = c; }
        __syncthreads();
        if (threadIdx.x == 0) {
            float tt = 0.0f, cc = 0.0f;
            #pragma unroll
            for (int i = 0; i < WAVES_PER_BLOCK; ++i) { tt += fT[i]; cc += fC[i]; }
            out[0] = (cc > 0.0f) ? (-tt / cc) : 0.0f;
        }
    }
}

extern "C" void kernel_launch(void* const* d_in, const int* in_sizes, int n_in,
                              void* d_out, int out_size, void* d_ws, size_t ws_size,
                              hipStream_t stream) {
    const float* pred = (const float*)d_in[0];
    const float* mask = (const float*)d_in[1];
    float* out = (float*)d_out;
    unsigned long long* partial = (unsigned long long*)d_ws;
    unsigned int* ticket = (unsigned int*)(partial + NBLOCKS);

    const int N = in_sizes[0] / NCLS;    // number of rows (T*B)

    pl_fused<<<NBLOCKS, NTHREADS, 0, stream>>>(pred, mask, partial, ticket, out, N);
}

// Round 9
// 49.043 us; speedup vs baseline: 1.0842x; 1.0842x over previous
//
#include <hip/hip_runtime.h>

// pred: [T=2048, B=64, C=512] f32, mask: [T*B, 1] f32.
// loss = -sum_{p>0.9} p / max(cnt,1), 0 if cnt==0.
// Only the per-row argmax can exceed 0.9 (softmax sums to 1), so per row:
//   m = max(x), s = sum exp(x-m), pmax = 1/s; selected iff pmax > 0.9.
//
// Final structure (best measured = R2, 49.3us):
//   - two kernels: streaming reduce -> per-block partials (plain stores,
//     no init kernel), then a tiny 1-block finalize. Fused single-kernel
//     variants (R6/R8) consistently cost +3.5-4us regardless of block
//     count: device-side last-block reduction over uncached agent-scope
//     loads + per-block vmcnt(0)+ticket tail loses to a ~2us second node.
//   - plain cached f32x4 loads (R4: nontemporal loads collapse streaming
//     BW ~10x on gfx950 — cached path IS the fast path).
//   - no acq_rel/threadfence publish (R5: per-block L2 writeback+inv
//     serializes, +125-245us).
//   - grid-stride row assignment, unroll x2 (R7: contiguous partition is
//     neutral — DRAM locality not the limiter at 8192 concurrent streams).
// Main loop runs at ~5.9 TB/s apparent (93% of 6.29 TB/s measured copy
// ceiling); total = stream floor 42.8us + ~2-4us second node + ramp.

#define NCLS 512
#define THRESH 0.9f
#define NBLOCKS 2048

typedef float f32x4 __attribute__((ext_vector_type(4)));

__device__ __forceinline__ void row_reduce(f32x4 a, f32x4 b, float mval,
                                           float& wTotal, float& wCnt) {
    float x0 = a.x * mval, x1 = a.y * mval, x2 = a.z * mval, x3 = a.w * mval;
    float x4 = b.x * mval, x5 = b.y * mval, x6 = b.z * mval, x7 = b.w * mval;

    float mx = fmaxf(fmaxf(fmaxf(x0, x1), fmaxf(x2, x3)),
                     fmaxf(fmaxf(x4, x5), fmaxf(x6, x7)));
    #pragma unroll
    for (int off = 1; off < 64; off <<= 1)
        mx = fmaxf(mx, __shfl_xor(mx, off));

    float s = __expf(x0 - mx) + __expf(x1 - mx) + __expf(x2 - mx) + __expf(x3 - mx)
            + __expf(x4 - mx) + __expf(x5 - mx) + __expf(x6 - mx) + __expf(x7 - mx);
    #pragma unroll
    for (int off = 1; off < 64; off <<= 1)
        s += __shfl_xor(s, off);

    float pmax = 1.0f / s;          // prob of the argmax element
    if (pmax > THRESH) { wTotal += pmax; wCnt += 1.0f; }
}

__global__ __launch_bounds__(256) void pl_main(const float* __restrict__ pred,
                                               const float* __restrict__ mask,
                                               float2* __restrict__ partial,
                                               int N) {
    const int lane = threadIdx.x & 63;
    const int wid  = threadIdx.x >> 6;   // 4 waves per block

    float wTotal = 0.0f;
    float wCnt   = 0.0f;

    const long long rstride = (long long)gridDim.x * 4;
    long long row = (long long)blockIdx.x * 4 + wid;

    // unroll x2: two rows' loads (4x 16B/lane) in flight before either
    // row's dependent shuffle/exp chain starts
    for (; row + rstride < (long long)N; row += 2 * rstride) {
        const long long r2 = row + rstride;
        const float m1 = mask[row];
        const float m2 = mask[r2];
        const f32x4* rp1 = (const f32x4*)(pred + row * NCLS);
        const f32x4* rp2 = (const f32x4*)(pred + r2 * NCLS);
        f32x4 a1 = rp1[lane];
        f32x4 b1 = rp1[lane + 64];
        f32x4 a2 = rp2[lane];
        f32x4 b2 = rp2[lane + 64];
        row_reduce(a1, b1, m1, wTotal, wCnt);
        row_reduce(a2, b2, m2, wTotal, wCnt);
    }
    for (; row < (long long)N; row += rstride) {
        const float m1 = mask[row];
        const f32x4* rp1 = (const f32x4*)(pred + row * NCLS);
        f32x4 a1 = rp1[lane];
        f32x4 b1 = rp1[lane + 64];
        row_reduce(a1, b1, m1, wTotal, wCnt);
    }

    __shared__ float sT[4];
    __shared__ float sC[4];
    if (lane == 0) { sT[wid] = wTotal; sC[wid] = wCnt; }
    __syncthreads();
    if (threadIdx.x == 0) {
        float t = sT[0] + sT[1] + sT[2] + sT[3];
        float c = sC[0] + sC[1] + sC[2] + sC[3];
        partial[blockIdx.x] = make_float2(t, c);
    }
}

__global__ __launch_bounds__(256) void pl_final(const float2* __restrict__ partial,
                                                int nb, float* __restrict__ out) {
    const int lane = threadIdx.x & 63;
    const int wid  = threadIdx.x >> 6;

    float t = 0.0f, c = 0.0f;
    for (int i = threadIdx.x; i < nb; i += 256) {
        float2 p = partial[i];
        t += p.x;
        c += p.y;
    }
    #pragma unroll
    for (int off = 1; off < 64; off <<= 1) {
        t += __shfl_xor(t, off);
        c += __shfl_xor(c, off);
    }
    __shared__ float sT[4];
    __shared__ float sC[4];
    if (lane == 0) { sT[wid] = t; sC[wid] = c; }
    __syncthreads();
    if (threadIdx.x == 0) {
        float tt = sT[0] + sT[1] + sT[2] + sT[3];
        float cc = sC[0] + sC[1] + sC[2] + sC[3];
        out[0] = (cc > 0.0f) ? (-tt / cc) : 0.0f;
    }
}

extern "C" void kernel_launch(void* const* d_in, const int* in_sizes, int n_in,
                              void* d_out, int out_size, void* d_ws, size_t ws_size,
                              hipStream_t stream) {
    const float* pred = (const float*)d_in[0];
    const float* mask = (const float*)d_in[1];
    float* out = (float*)d_out;
    float2* partial = (float2*)d_ws;

    const int N = in_sizes[0] / NCLS;    // number of rows (T*B)

    pl_main<<<NBLOCKS, 256, 0, stream>>>(pred, mask, partial, N);
    pl_final<<<1, 256, 0, stream>>>(partial, NBLOCKS, out);
}